// Round 17
// baseline (68.940 us; speedup 1.0000x reference)
//
#include <hip/hip_runtime.h>

// Problem constants (fixed by reference)
constexpr int Bn = 4, Cn = 64, Hn = 192, Wn = 640, HW = Hn * Wn;
constexpr int TH = 8, TW = 64;            // output tile per block
constexpr int SH = TH + 4;                // 12 tile+halo rows
constexpr int SW = TW + 4;                // 68
constexpr int NS = SH * SW;               // 816
constexpr int NP = NS / 2;                // 408 staging pairs
constexpr int PPR = SW / 2;               // 34 pairs per row
constexpr int NT = 256;                   // 4 waves; quads + dual-job staging
constexpr int CH = 4;                     // channels staged per chunk
constexpr int NCHUNK = Cn / CH;           // 16
constexpr int DR = SH - 2;                // 10 forward-dot rows
constexpr int ND = DR * SW;               // 680 forward-domain pixels
constexpr int NQUAD = (DR / 2) * PPR;     // 170 quad threads (2x2 px each)
constexpr int ARENA = 12 * ND;            // 8160 floats = 32.6 KB (>= slices 6528)

// Relaxed barrier (T4): ds-writes visible via lgkmcnt(0); global loads stay
// in flight across the barrier (no vmcnt(0) drain, unlike __syncthreads).
#define SYNC_RELAXED() do {                                   \
    asm volatile("s_waitcnt lgkmcnt(0)" ::: "memory");        \
    __builtin_amdgcn_s_barrier();                             \
    asm volatile("" ::: "memory");                            \
} while (0)

// NOTE: min-waves-per-EU > 4 spills (R11). LDS=39.4KB caps blocks/CU at 4,
// so (256,4) admits up to 128 VGPR - room for 48 accs + 22 temps.
__global__ __launch_bounds__(NT, 4) void guide_triplet_kernel(
    const float* __restrict__ pred,
    const int*   __restrict__ target,
    float* __restrict__ out)
{
    __shared__ float arena[ARENA];
    __shared__ float invnS[NS + 4];   // +4 pad: benign OOB publish reads
    __shared__ int   lblS[NS];

    const int x0 = blockIdx.x * TW;
    const int y0 = blockIdx.y * TH;
    const int b  = blockIdx.z;

    const int tid = threadIdx.x;

    // ---- staging: pair j0 = tid (all), pair j1 = tid+256 (tid < 152) ----
    const int j0 = tid, j1 = tid + NT;
    const bool has1 = (j1 < NP);
    const int sr0 = j0 / PPR, sc0 = j0 - sr0 * PPR;
    const int sr1 = j1 / PPR, sc1 = j1 - sr1 * PPR;
    const int gy0 = y0 + sr0 - 2, gx0 = x0 + 2 * sc0 - 2;
    const int gy1 = y0 + sr1 - 2, gx1 = x0 + 2 * sc1 - 2;
    const bool ok0 = (gy0 >= 0) && (gy0 < Hn) && (gx0 >= 0) && (gx0 + 1 < Wn);
    const bool ok1 = has1 && (gy1 >= 0) && (gy1 < Hn) && (gx1 >= 0) && (gx1 + 1 < Wn);
    const int go0 = gy0 * Wn + gx0;
    const int go1 = gy1 * Wn + gx1;

    // ---- labels once (pad = -1) ----
    {
        const int* tb = target + b * HW;
        int lx = -1, ly = -1;
        if (ok0) { const int2 L = *reinterpret_cast<const int2*>(tb + go0); lx = L.x; ly = L.y; }
        lblS[2 * j0]     = lx;
        lblS[2 * j0 + 1] = ly;
        if (has1) {
            int mx = -1, my = -1;
            if (ok1) { const int2 L = *reinterpret_cast<const int2*>(tb + go1); mx = L.x; my = L.y; }
            lblS[2 * j1]     = mx;
            lblS[2 * j1 + 1] = my;
        }
    }
    if (tid < 4) invnS[NS + tid] = 1.0f;      // init pad

    // ---- quad mapping: thread -> 2x2 pixels at (2q, 2pj) ----
    const bool isQuad = (tid < NQUAD);
    const int q  = tid / PPR;         // 0..4  -> rows 2q, 2q+1
    const int pj = tid - q * PPR;     // 0..33 -> cols 2pj, 2pj+1

    float ssx0 = 0.f, ssy0 = 0.f, ssx1 = 0.f, ssy1 = 0.f;
    float accA[12], accB[12], accC[12], accD[12];
    #pragma unroll
    for (int i = 0; i < 12; ++i) { accA[i]=0.f; accB[i]=0.f; accC[i]=0.f; accD[i]=0.f; }

    const float* predb = pred + (size_t)b * Cn * HW;

    float2 ld0[CH], ld1[CH];          // depth-1 prefetch

#define LOADCHUNK(CHUNK) do {                                               \
    _Pragma("unroll")                                                       \
    for (int cc = 0; cc < CH; ++cc) {                                       \
        const float* pc_ = predb + (size_t)((CHUNK) * CH + cc) * HW;        \
        float2 v = make_float2(0.f, 0.f), w = make_float2(0.f, 0.f);        \
        if (ok0) v = *reinterpret_cast<const float2*>(pc_ + go0);           \
        if (ok1) w = *reinterpret_cast<const float2*>(pc_ + go1);           \
        ld0[cc] = v; ld1[cc] = w;                                           \
    } } while (0)

    LOADCHUNK(0);

    for (int chunk = 0; chunk < NCHUNK; ++chunk) {
        float* sb = arena + (chunk & 1) * (CH * NS);

        // W(k): regs -> LDS (ds_write_b64), fold sumsq
        #pragma unroll
        for (int cc = 0; cc < CH; ++cc) {
            const float2 v = ld0[cc];
            *reinterpret_cast<float2*>(&sb[cc * NS + 2 * j0]) = v;
            ssx0 = fmaf(v.x, v.x, ssx0);
            ssy0 = fmaf(v.y, v.y, ssy0);
            if (has1) {
                const float2 w = ld1[cc];
                *reinterpret_cast<float2*>(&sb[cc * NS + 2 * j1]) = w;
                ssx1 = fmaf(w.x, w.x, ssx1);
                ssy1 = fmaf(w.y, w.y, ssy1);
            }
        }
        SYNC_RELAXED();

        // L(k+1): depth-1 prefetch; stays in flight through C(k) (no drain)
        if (chunk + 1 < NCHUNK) LOADCHUNK(chunk + 1);

        // C(k): 2x2 quad - 22 words in 11 ds_read_b64 + 48 FMA per channel.
        // unroll 1: keep ONE channel's temps live (spill avoidance).
        if (isQuad) {
            #pragma unroll 1
            for (int cc = 0; cc < CH; ++cc) {
                const float* s0 = sb + cc * NS + (2 * q) * SW + 2 * pj;
                const float w00 = s0[0], w01 = s0[1], w02 = s0[2], w03 = s0[3];
                const float* s1 = s0 + (SW - 2);
                const float w10 = s1[0], w11 = s1[1], w12 = s1[2],
                            w13 = s1[3], w14 = s1[4], w15 = s1[5];
                const float* s2 = s1 + SW;
                const float w20 = s2[0], w21 = s2[1], w22 = s2[2],
                            w23 = s2[3], w24 = s2[4], w25 = s2[5];
                const float* s3 = s2 + SW;
                const float w30 = s3[0], w31 = s3[1], w32 = s3[2],
                            w33 = s3[3], w34 = s3[4], w35 = s3[5];
                // A = (2q, 2pj), center w00
                accA[0]  = fmaf(w00, w01, accA[0]);
                accA[1]  = fmaf(w00, w02, accA[1]);
                accA[2]  = fmaf(w00, w10, accA[2]);
                accA[3]  = fmaf(w00, w11, accA[3]);
                accA[4]  = fmaf(w00, w12, accA[4]);
                accA[5]  = fmaf(w00, w13, accA[5]);
                accA[6]  = fmaf(w00, w14, accA[6]);
                accA[7]  = fmaf(w00, w20, accA[7]);
                accA[8]  = fmaf(w00, w21, accA[8]);
                accA[9]  = fmaf(w00, w22, accA[9]);
                accA[10] = fmaf(w00, w23, accA[10]);
                accA[11] = fmaf(w00, w24, accA[11]);
                // B = (2q, 2pj+1), center w01
                accB[0]  = fmaf(w01, w02, accB[0]);
                accB[1]  = fmaf(w01, w03, accB[1]);
                accB[2]  = fmaf(w01, w11, accB[2]);
                accB[3]  = fmaf(w01, w12, accB[3]);
                accB[4]  = fmaf(w01, w13, accB[4]);
                accB[5]  = fmaf(w01, w14, accB[5]);
                accB[6]  = fmaf(w01, w15, accB[6]);
                accB[7]  = fmaf(w01, w21, accB[7]);
                accB[8]  = fmaf(w01, w22, accB[8]);
                accB[9]  = fmaf(w01, w23, accB[9]);
                accB[10] = fmaf(w01, w24, accB[10]);
                accB[11] = fmaf(w01, w25, accB[11]);
                // C = (2q+1, 2pj), center w12
                accC[0]  = fmaf(w12, w13, accC[0]);
                accC[1]  = fmaf(w12, w14, accC[1]);
                accC[2]  = fmaf(w12, w20, accC[2]);
                accC[3]  = fmaf(w12, w21, accC[3]);
                accC[4]  = fmaf(w12, w22, accC[4]);
                accC[5]  = fmaf(w12, w23, accC[5]);
                accC[6]  = fmaf(w12, w24, accC[6]);
                accC[7]  = fmaf(w12, w30, accC[7]);
                accC[8]  = fmaf(w12, w31, accC[8]);
                accC[9]  = fmaf(w12, w32, accC[9]);
                accC[10] = fmaf(w12, w33, accC[10]);
                accC[11] = fmaf(w12, w34, accC[11]);
                // D = (2q+1, 2pj+1), center w13
                accD[0]  = fmaf(w13, w14, accD[0]);
                accD[1]  = fmaf(w13, w15, accD[1]);
                accD[2]  = fmaf(w13, w21, accD[2]);
                accD[3]  = fmaf(w13, w22, accD[3]);
                accD[4]  = fmaf(w13, w23, accD[4]);
                accD[5]  = fmaf(w13, w24, accD[5]);
                accD[6]  = fmaf(w13, w25, accD[6]);
                accD[7]  = fmaf(w13, w31, accD[7]);
                accD[8]  = fmaf(w13, w32, accD[8]);
                accD[9]  = fmaf(w13, w33, accD[9]);
                accD[10] = fmaf(w13, w34, accD[10]);
                accD[11] = fmaf(w13, w35, accD[11]);
            }
        }
        // no tail barrier: double buffer + next iteration's barrier protect reuse
    }

    // ---- inverse norms ----
    invnS[2 * j0]     = 1.0f / fmaxf(sqrtf(ssx0), 1e-12f);
    invnS[2 * j0 + 1] = 1.0f / fmaxf(sqrtf(ssy0), 1e-12f);
    if (has1) {
        invnS[2 * j1]     = 1.0f / fmaxf(sqrtf(ssx1), 1e-12f);
        invnS[2 * j1 + 1] = 1.0f / fmaxf(sqrtf(ssy1), 1e-12f);
    }
    __syncthreads();   // C reads done; invn visible; arena reusable

    constexpr int DIRD[12] = {1, 2, SW - 2, SW - 1, SW, SW + 1, SW + 2,
                              2 * SW - 2, 2 * SW - 1, 2 * SW, 2 * SW + 1, 2 * SW + 2};

    // ---- publish AFFINITY planes (each pair affinity computed ONCE) ----
    if (isQuad) {
        const int qA = (2 * q) * SW + 2 * pj;
        const int qB = qA + 1;
        const int qC = qA + SW;
        const int qD = qC + 1;
        const float icA = invnS[qA], icB = invnS[qB];
        const float icC = invnS[qC], icD = invnS[qD];
        #pragma unroll
        for (int k = 0; k < 12; ++k) {
            const int dq = DIRD[k];
            const float sA = accA[k] * icA * invnS[qA + dq];
            const float sB = accB[k] * icB * invnS[qB + dq];
            const float sC = accC[k] * icC * invnS[qC + dq];
            const float sD = accD[k] * icD * invnS[qD + dq];
            arena[k * ND + qA] = sqrtf(fmaxf(1e-9f, fmaf(-2.0f, sA, 2.0f)));
            arena[k * ND + qB] = sqrtf(fmaxf(1e-9f, fmaf(-2.0f, sB, 2.0f)));
            arena[k * ND + qC] = sqrtf(fmaxf(1e-9f, fmaf(-2.0f, sC, 2.0f)));
            arena[k * ND + qD] = sqrtf(fmaxf(1e-9f, fmaf(-2.0f, sD, 2.0f)));
        }
    }
    __syncthreads();

    // ---- epilogue: 2 output pixels per thread, compare+add only ----
    #pragma unroll
    for (int half = 0; half < 2; ++half) {
        const int e   = tid + half * NT;          // 0..511
        const int row = e >> 6, col = e & 63;
        const int qp  = (2 + row) * SW + (2 + col);
        const int lc  = lblS[qp];
        float tot = 0.0f, ps = 0.0f, pn = 0.0f;
        #pragma unroll
        for (int k = 0; k < 12; ++k) {
            const int dq = DIRD[k];
            const float affF = arena[k * ND + qp];
            const float affB = arena[k * ND + qp - dq];
            const float mfF = (lblS[qp + dq] == lc) ? 1.0f : 0.0f;
            const float mfB = (lblS[qp - dq] == lc) ? 1.0f : 0.0f;
            tot += affF + affB;
            pn += mfF + mfB;
            ps = fmaf(mfF, affF, fmaf(mfB, affB, ps));
        }
        const float pos_num = pn + 1.0f;
        const float pos_sum = ps + 3.16227766e-5f;   // self: aff=sqrt(1e-9)
        const float neg_num = 24.0f - pn;
        const float neg_sum = tot - ps;
        const bool boundary = (pos_num >= 4.0f) && (neg_num >= 4.0f);
        const float tri = fmaxf(0.0f,
            pos_sum / pos_num - neg_sum / fmaxf(neg_num, 1e-12f) + 0.3f);
        out[((size_t)b * Hn + (y0 + row)) * Wn + (x0 + col)] = boundary ? tri : 0.0f;
    }
}

extern "C" void kernel_launch(void* const* d_in, const int* in_sizes, int n_in,
                              void* d_out, int out_size, void* d_ws, size_t ws_size,
                              hipStream_t stream) {
    const float* pred   = (const float*)d_in[0];
    const int*   target = (const int*)d_in[1];
    float*       out    = (float*)d_out;
    dim3 grid(Wn / TW, Hn / TH, Bn);   // 10 x 24 x 4 = 960 blocks
    guide_triplet_kernel<<<grid, NT, 0, stream>>>(pred, target, out);
}